// Round 4
// baseline (1914.772 us; speedup 1.0000x reference)
//
#include <hip/hip_runtime.h>
#include <hip/hip_bf16.h>

#define NB 2
#define NS 4096
#define NE 512
#define NH 8
#define ND 64
#define NHD 512

typedef __attribute__((ext_vector_type(8))) short short8;
typedef __attribute__((ext_vector_type(4))) float floatx4;
typedef unsigned long long u64;
typedef unsigned int u32;
typedef unsigned short u16;
typedef unsigned char u8;

#define MFMA16(a, b, c) __builtin_amdgcn_mfma_f32_16x16x32_bf16((a), (b), (c), 0, 0, 0)

union Cvt8 { uint4 u; short8 s; };
static __device__ __forceinline__ short8 ld8(const __hip_bfloat16* p) {
  Cvt8 c; c.u = *(const uint4*)p; return c.s;
}
union BH { __hip_bfloat16 h; short s; };
static __device__ __forceinline__ short f2bs(float x) {
  BH u; u.h = __float2bfloat16(x); return u.s;
}

// ---------------------------------------------------------------------------
// Kernel 0: sniff input dtypes from bit patterns; write flags to ws.
// flags[0] = fmode: 0 = float inputs are bf16, 1 = float inputs are f32
// flags[1] = mmode: 0 = mask int32, 1 = mask int8/bool, 2 = mask bf16
// Rationale: true-bf16 N(0,1) data has no element with |x|>=64 (exp>=133);
// f32 data misread as bf16 has ~48% such ushorts in the low halves.
// ---------------------------------------------------------------------------
__global__ __launch_bounds__(256) void sniff(const u16* qb, const u32* mw, int* flags) {
  __shared__ int sh[3];
  if (threadIdx.x < 3) sh[threadIdx.x] = 0;
  __syncthreads();
  int bad = 0;
  for (int i = threadIdx.x; i < 2048; i += 256) {
    const int e = (qb[i] >> 7) & 0xFF;
    if (e >= 133) bad++;                       // |x|>=64 or NaN/Inf pattern
  }
  int g1 = 0, ob = 0;
  for (int i = threadIdx.x; i < 1024; i += 256) {
    const u32 v = mw[i];
    if (v > 1u) g1++;                          // impossible for int32 0/1 mask
    if ((v & 0xFF) > 1 || ((v >> 8) & 0xFF) > 1 ||
        ((v >> 16) & 0xFF) > 1 || ((v >> 24) & 0xFF) > 1) ob++;  // non-{0,1} byte
  }
  if (bad) atomicAdd(&sh[0], bad);
  if (g1) atomicAdd(&sh[1], g1);
  if (ob) atomicAdd(&sh[2], ob);
  __syncthreads();
  if (threadIdx.x == 0) {
    flags[0] = (sh[0] > 16) ? 1 : 0;
    flags[1] = (sh[1] == 0) ? 0 : ((sh[2] > 0) ? 2 : 1);
  }
}

// ---------------------------------------------------------------------------
// Kernel 1: convert + transpose 512x512 weights (either dtype) -> bf16 W^T.
// Sanitizes non-finite values to 0 (belt and suspenders).
// ---------------------------------------------------------------------------
__global__ __launch_bounds__(256) void wconv(
    const void* w0, const void* w1, const void* w2, const void* w3,
    const int* flags,
    __hip_bfloat16* t0, __hip_bfloat16* t1,
    __hip_bfloat16* t2, __hip_bfloat16* t3) {
  __shared__ __hip_bfloat16 tile[64][72];
  const void* src;
  __hip_bfloat16* dst;
  switch (blockIdx.z) {
    case 0: src = w0; dst = t0; break;
    case 1: src = w1; dst = t1; break;
    case 2: src = w2; dst = t2; break;
    default: src = w3; dst = t3; break;
  }
  const int fm = flags[0];
  const int tx = threadIdx.x & 63, ty = threadIdx.x >> 6;
  const int n0 = blockIdx.x * 64, k0 = blockIdx.y * 64;
  for (int r = ty; r < 64; r += 4) {
    const long idx = (long)(k0 + r) * 512 + n0 + tx;
    float v = fm ? ((const float*)src)[idx]
                 : __bfloat162float(((const __hip_bfloat16*)src)[idx]);
    if (!__builtin_isfinite(v)) v = 0.f;
    tile[r][tx] = __float2bfloat16(v);
  }
  __syncthreads();
  for (int r = ty; r < 64; r += 4)
    dst[(long)(n0 + r) * 512 + k0 + tx] = tile[tx][r];
}

// ---------------------------------------------------------------------------
// Kernel 2: pack mask (any encoding) into bit form: bits[row*64 + kt] bit j
// <=> mask[row][kt*64+j] nonzero.  One block per (b,h,q) row; wave ballots.
// ---------------------------------------------------------------------------
__global__ __launch_bounds__(256) void mconv(const void* mask, const int* flags, u64* bits) {
  const int tid = threadIdx.x, lane = tid & 63, w = tid >> 6;
  const long row = blockIdx.x;
  const int mm = flags[1];
  const long b0 = row * NS;
  if (mm == 0) {
    const u32* m = (const u32*)mask;
#pragma unroll
    for (int i = 0; i < 16; ++i) {
      const int kt = w + 4 * i;
      const u64 bl = __ballot(m[b0 + kt * 64 + lane] != 0u);
      if (lane == 0) bits[row * 64 + kt] = bl;
    }
  } else if (mm == 1) {
    const u8* m = (const u8*)mask;
#pragma unroll
    for (int i = 0; i < 16; ++i) {
      const int kt = w + 4 * i;
      const u64 bl = __ballot(m[b0 + kt * 64 + lane] != 0);
      if (lane == 0) bits[row * 64 + kt] = bl;
    }
  } else {
    const u16* m = (const u16*)mask;
#pragma unroll
    for (int i = 0; i < 16; ++i) {
      const int kt = w + 4 * i;
      const u64 bl = __ballot(m[b0 + kt * 64 + lane] != 0);
      if (lane == 0) bits[row * 64 + kt] = bl;
    }
  }
}

// ---------------------------------------------------------------------------
// Kernel 3/5: GEMM  C[M x 512] = A[M x 512] @ W  (W passed transposed bf16).
// A read as bf16 or f32 per flags (a_raw) ; output f32/bf16 per out_fmode.
// layout 0: row-major out.  layout 1: (B,H,S,D) scatter for q/k/v.
// ---------------------------------------------------------------------------
__global__ __launch_bounds__(256) void gemm_proj(
    const void* A0, const void* A1, const void* A2,
    const __hip_bfloat16* W0, const __hip_bfloat16* W1, const __hip_bfloat16* W2,
    void* O0, void* O1, void* O2,
    const int* flags, int a_raw, int out_fmode, int layout) {
  const void* A;
  const __hip_bfloat16* Wt;
  void* O;
  switch (blockIdx.z) {
    case 0: A = A0; Wt = W0; O = O0; break;
    case 1: A = A1; Wt = W1; O = O1; break;
    default: A = A2; Wt = W2; O = O2; break;
  }
  const int fm = a_raw ? flags[0] : 0;
  const int lane = threadIdx.x & 63;
  const int w = threadIdx.x >> 6;
  const int c = lane & 15, g = lane >> 4;
  const int m0 = blockIdx.x * 64 + w * 16;
  const int n0 = blockIdx.y * 64;

  floatx4 acc[4] = {};
  const __hip_bfloat16* wp = Wt + (long)(n0 + c) * 512 + g * 8;
  if (fm == 0) {
    const __hip_bfloat16* ap = (const __hip_bfloat16*)A + (long)(m0 + c) * 512 + g * 8;
    for (int ks = 0; ks < 512; ks += 32) {
      short8 a = ld8(ap + ks);
#pragma unroll
      for (int t = 0; t < 4; ++t) {
        short8 b = ld8(wp + t * 16 * 512 + ks);
        acc[t] = MFMA16(a, b, acc[t]);
      }
    }
  } else {
    const float* ap = (const float*)A + (long)(m0 + c) * 512 + g * 8;
    for (int ks = 0; ks < 512; ks += 32) {
      const float4 f0 = *(const float4*)(ap + ks);
      const float4 f1 = *(const float4*)(ap + ks + 4);
      short8 a;
      a[0] = f2bs(f0.x); a[1] = f2bs(f0.y); a[2] = f2bs(f0.z); a[3] = f2bs(f0.w);
      a[4] = f2bs(f1.x); a[5] = f2bs(f1.y); a[6] = f2bs(f1.z); a[7] = f2bs(f1.w);
#pragma unroll
      for (int t = 0; t < 4; ++t) {
        short8 b = ld8(wp + t * 16 * 512 + ks);
        acc[t] = MFMA16(a, b, acc[t]);
      }
    }
  }
  const int om = out_fmode ? flags[0] : 0;
#pragma unroll
  for (int t = 0; t < 4; ++t) {
#pragma unroll
    for (int r = 0; r < 4; ++r) {
      const int m = m0 + g * 4 + r;
      const int n = n0 + t * 16 + c;
      const float v = acc[t][r];
      if (layout == 0) {
        if (om) ((float*)O)[(long)m * 512 + n] = v;
        else ((__hip_bfloat16*)O)[(long)m * 512 + n] = __float2bfloat16(v);
      } else {
        const int bb = m >> 12, s = m & 4095, h = n >> 6, d = n & 63;
        ((__hip_bfloat16*)O)[(((long)bb * NH + h) * NS + s) * ND + d] = __float2bfloat16(v);
      }
    }
  }
}

// ---------------------------------------------------------------------------
// Kernel 4: fused flash attention, mask from packed bits.
// grid (S/64, H, B); block 256 = 4 waves; wave handles 16 q-rows.
// ---------------------------------------------------------------------------
#define VPAD 72
__device__ __forceinline__ int vswz(int row) { return ((row >> 3) & 7) * 8; }

__global__ __launch_bounds__(256) void flash_attn(
    const __hip_bfloat16* Q, const __hip_bfloat16* K, const __hip_bfloat16* V,
    const u64* mb, __hip_bfloat16* AO) {
  __shared__ __hip_bfloat16 Ks[64 * VPAD];
  __shared__ __hip_bfloat16 Vt[64 * VPAD];
  __shared__ __hip_bfloat16 Pb[4 * 16 * VPAD];

  const int tid = threadIdx.x;
  const int lane = tid & 63, w = tid >> 6;
  const int c = lane & 15, g = lane >> 4;
  const int bz = blockIdx.z, hy = blockIdx.y;
  const int q0 = blockIdx.x * 64 + w * 16;
  const long headbase = ((long)bz * NH + hy) * NS;

  const short8 qf0 = ld8(Q + (headbase + q0 + c) * ND + g * 8);
  const short8 qf1 = ld8(Q + (headbase + q0 + c) * ND + 32 + g * 8);

  floatx4 oacc[4] = {};
  float m_i[4], l_i[4];
#pragma unroll
  for (int r = 0; r < 4; ++r) { m_i[r] = -1e30f; l_i[r] = 0.f; }
  __hip_bfloat16* Pw = Pb + w * 16 * VPAD;

  for (int kt = 0; kt < 64; ++kt) {
    const int k0 = kt * 64;
#pragma unroll
    for (int it = 0; it < 2; ++it) {
      const int chunk = tid + it * 256;
      const int kc = chunk >> 3;
      const int dd = (chunk & 7) * 8;
      const long gbase = (headbase + k0 + kc) * ND + dd;
      *(uint4*)&Ks[kc * VPAD + dd] = *(const uint4*)(K + gbase);
      uint4 vv = *(const uint4*)(V + gbase);
      const __hip_bfloat16* ve = (const __hip_bfloat16*)&vv;
#pragma unroll
      for (int j = 0; j < 8; ++j) {
        const int row = dd + j;
        Vt[row * VPAD + (kc ^ vswz(row))] = ve[j];
      }
    }
    __syncthreads();

    // ---- S = Q K^T ----
    floatx4 sacc[4] = {};
#pragma unroll
    for (int t = 0; t < 4; ++t) {
      short8 b0 = ld8(&Ks[(t * 16 + c) * VPAD + g * 8]);
      sacc[t] = MFMA16(qf0, b0, sacc[t]);
      short8 b1 = ld8(&Ks[(t * 16 + c) * VPAD + 32 + g * 8]);
      sacc[t] = MFMA16(qf1, b1, sacc[t]);
    }

    // ---- mask (bit-packed) + online softmax ----
    float alpha[4];
#pragma unroll
    for (int r = 0; r < 4; ++r) {
      const int qrow = q0 + g * 4 + r;
      const u64 w64 = mb[(headbase + qrow) * 64 + kt];
      float mx = -1e30f;
#pragma unroll
      for (int t = 0; t < 4; ++t) {
        float s = sacc[t][r] * 0.125f;
        if ((w64 >> (t * 16 + c)) & 1ULL) s = -1e10f;
        sacc[t][r] = s;
        mx = fmaxf(mx, s);
      }
#pragma unroll
      for (int off = 1; off < 16; off <<= 1)
        mx = fmaxf(mx, __shfl_xor(mx, off));
      const float mn = fmaxf(m_i[r], mx);
      const float al = __expf(m_i[r] - mn);
      float ps = 0.f;
#pragma unroll
      for (int t = 0; t < 4; ++t) {
        const float p = __expf(sacc[t][r] - mn);
        sacc[t][r] = p;
        ps += p;
      }
#pragma unroll
      for (int off = 1; off < 16; off <<= 1)
        ps += __shfl_xor(ps, off);
      m_i[r] = mn;
      l_i[r] = l_i[r] * al + ps;
      alpha[r] = al;
#pragma unroll
      for (int t = 0; t < 4; ++t)
        Pw[(g * 4 + r) * VPAD + t * 16 + c] = __float2bfloat16(sacc[t][r]);
    }

#pragma unroll
    for (int t = 0; t < 4; ++t)
#pragma unroll
      for (int r = 0; r < 4; ++r) oacc[t][r] *= alpha[r];

    // stop compiler hoisting the uint4 reads of Pw above the bf16 writes
    asm volatile("" ::: "memory");

#pragma unroll
    for (int ks2 = 0; ks2 < 2; ++ks2) {
      short8 af = ld8(&Pw[c * VPAD + ks2 * 32 + g * 8]);
#pragma unroll
      for (int t = 0; t < 4; ++t) {
        const int row = t * 16 + c;
        short8 bf = ld8(&Vt[row * VPAD + ((ks2 * 32 + g * 8) ^ vswz(row))]);
        oacc[t] = MFMA16(af, bf, oacc[t]);
      }
    }
    __syncthreads();
  }

#pragma unroll
  for (int t = 0; t < 4; ++t) {
#pragma unroll
    for (int r = 0; r < 4; ++r) {
      const int qrow = q0 + g * 4 + r;
      const float v = oacc[t][r] / l_i[r];
      AO[((long)bz * NS + qrow) * NHD + hy * 64 + t * 16 + c] = __float2bfloat16(v);
    }
  }
}

// ---------------------------------------------------------------------------
extern "C" void kernel_launch(void* const* d_in, const int* in_sizes, int n_in,
                              void* d_out, int out_size, void* d_ws, size_t ws_size,
                              hipStream_t stream) {
  char* base = (char*)d_ws;
  int* flags = (int*)base;
  const size_t MB = 1u << 20;
  __hip_bfloat16* wtq = (__hip_bfloat16*)(base + 1 * MB);
  __hip_bfloat16* wtk = (__hip_bfloat16*)(base + 1 * MB + 512 * 1024);
  __hip_bfloat16* wtv = (__hip_bfloat16*)(base + 2 * MB);
  __hip_bfloat16* wto = (__hip_bfloat16*)(base + 2 * MB + 512 * 1024);
  __hip_bfloat16* qp = (__hip_bfloat16*)(base + 3 * MB);    // 8 MB each
  __hip_bfloat16* kp = (__hip_bfloat16*)(base + 11 * MB);
  __hip_bfloat16* vp = (__hip_bfloat16*)(base + 19 * MB);
  __hip_bfloat16* ao = (__hip_bfloat16*)(base + 27 * MB);
  u64* mbits = (u64*)(base + 35 * MB);                      // 32 MB

  sniff<<<1, 256, 0, stream>>>((const u16*)d_in[0], (const u32*)d_in[3], flags);
  wconv<<<dim3(8, 8, 4), 256, 0, stream>>>(
      d_in[4], d_in[5], d_in[6], d_in[7], flags, wtq, wtk, wtv, wto);
  mconv<<<NB * NH * NS, 256, 0, stream>>>(d_in[3], flags, mbits);
  gemm_proj<<<dim3(128, 8, 3), 256, 0, stream>>>(
      d_in[0], d_in[1], d_in[2], wtq, wtk, wtv, qp, kp, vp,
      flags, /*a_raw=*/1, /*out_fmode=*/0, /*layout=*/1);
  flash_attn<<<dim3(NS / 64, NH, NB), 256, 0, stream>>>(qp, kp, vp, mbits, ao);
  gemm_proj<<<dim3(128, 8, 1), 256, 0, stream>>>(
      ao, ao, ao, wto, wto, wto, d_out, d_out, d_out,
      flags, /*a_raw=*/0, /*out_fmode=*/1, /*layout=*/0);
}

// Round 6
// 1907.121 us; speedup vs baseline: 1.0040x; 1.0040x over previous
//
#include <hip/hip_runtime.h>
#include <hip/hip_bf16.h>

#define NB 2
#define NS 4096
#define NE 512
#define NH 8
#define ND 64
#define NHD 512

typedef __attribute__((ext_vector_type(8))) short short8;
typedef __attribute__((ext_vector_type(4))) float floatx4;
typedef unsigned long long u64;
typedef unsigned int u32;

#define MFMA16(a, b, c) __builtin_amdgcn_mfma_f32_16x16x32_bf16((a), (b), (c), 0, 0, 0)

union Cvt8 { uint4 u; short8 s; };
static __device__ __forceinline__ short8 ld8(const __hip_bfloat16* p) {
  Cvt8 c; c.u = *(const uint4*)p; return c.s;
}
union BH { __hip_bfloat16 h; short s; };
static __device__ __forceinline__ short f2bs(float x) {
  BH u; u.h = __float2bfloat16(x); return u.s;
}

// ---------------------------------------------------------------------------
// Kernel 1: convert f32 -> bf16 and transpose 512x512 weights (W[k][n] -> Wt[n][k])
// ---------------------------------------------------------------------------
__global__ __launch_bounds__(256) void wconv(
    const float* w0, const float* w1, const float* w2, const float* w3,
    __hip_bfloat16* t0, __hip_bfloat16* t1,
    __hip_bfloat16* t2, __hip_bfloat16* t3) {
  __shared__ __hip_bfloat16 tile[64][72];
  const float* src;
  __hip_bfloat16* dst;
  switch (blockIdx.z) {
    case 0: src = w0; dst = t0; break;
    case 1: src = w1; dst = t1; break;
    case 2: src = w2; dst = t2; break;
    default: src = w3; dst = t3; break;
  }
  const int tx = threadIdx.x & 63, ty = threadIdx.x >> 6;
  const int n0 = blockIdx.x * 64, k0 = blockIdx.y * 64;
  for (int r = ty; r < 64; r += 4)
    tile[r][tx] = __float2bfloat16(src[(long)(k0 + r) * 512 + n0 + tx]);
  __syncthreads();
  for (int r = ty; r < 64; r += 4)
    dst[(long)(n0 + r) * 512 + k0 + tx] = tile[tx][r];
}

// ---------------------------------------------------------------------------
// Kernel 2: pack int32 mask into bits: bits[row*64+kt] bit j <=> mask[row][kt*64+j]
// One block per (b,h,q) row; 4 waves ballot 16 key-tiles each.
// ---------------------------------------------------------------------------
__global__ __launch_bounds__(256) void mconv(const int* mask, u64* bits) {
  const int lane = threadIdx.x & 63, w = threadIdx.x >> 6;
  const long row = blockIdx.x;
  const long b0 = row * NS;
#pragma unroll
  for (int i = 0; i < 16; ++i) {
    const int kt = w + 4 * i;
    const u64 bl = __ballot(mask[b0 + kt * 64 + lane] != 0);
    if (lane == 0) bits[row * 64 + kt] = bl;
  }
}

// ---------------------------------------------------------------------------
// Kernel 3: QKV projection GEMM.  A (f32, M x 512) @ W^T (bf16, 512 x 512)
// -> q/k/v in (B,H,S,D) bf16.  grid (M/64, 8, 3); 4 waves/block.
// ---------------------------------------------------------------------------
__global__ __launch_bounds__(256) void gemm_qkv(
    const float* A0, const float* A1, const float* A2,
    const __hip_bfloat16* W0, const __hip_bfloat16* W1, const __hip_bfloat16* W2,
    __hip_bfloat16* O0, __hip_bfloat16* O1, __hip_bfloat16* O2) {
  const float* A;
  const __hip_bfloat16* Wt;
  __hip_bfloat16* O;
  switch (blockIdx.z) {
    case 0: A = A0; Wt = W0; O = O0; break;
    case 1: A = A1; Wt = W1; O = O1; break;
    default: A = A2; Wt = W2; O = O2; break;
  }
  const int lane = threadIdx.x & 63;
  const int w = threadIdx.x >> 6;
  const int c = lane & 15, g = lane >> 4;
  const int m0 = blockIdx.x * 64 + w * 16;
  const int n0 = blockIdx.y * 64;

  floatx4 acc[4] = {};
  const float* ap = A + (long)(m0 + c) * 512 + g * 8;
  const __hip_bfloat16* wp = Wt + (long)(n0 + c) * 512 + g * 8;
  for (int ks = 0; ks < 512; ks += 32) {
    const float4 f0 = *(const float4*)(ap + ks);
    const float4 f1 = *(const float4*)(ap + ks + 4);
    short8 a;
    a[0] = f2bs(f0.x); a[1] = f2bs(f0.y); a[2] = f2bs(f0.z); a[3] = f2bs(f0.w);
    a[4] = f2bs(f1.x); a[5] = f2bs(f1.y); a[6] = f2bs(f1.z); a[7] = f2bs(f1.w);
#pragma unroll
    for (int t = 0; t < 4; ++t) {
      short8 b = ld8(wp + t * 16 * 512 + ks);
      acc[t] = MFMA16(a, b, acc[t]);
    }
  }
#pragma unroll
  for (int t = 0; t < 4; ++t) {
#pragma unroll
    for (int r = 0; r < 4; ++r) {
      const int m = m0 + g * 4 + r;
      const int n = n0 + t * 16 + c;
      const int bb = m >> 12, s = m & 4095, h = n >> 6, d = n & 63;
      O[(((long)bb * NH + h) * NS + s) * ND + d] = __float2bfloat16(acc[t][r]);
    }
  }
}

// ---------------------------------------------------------------------------
// Kernel 4: fused flash attention; mask from packed bits.
// grid (S/64, H, B); block 256 = 4 waves; wave handles 16 q-rows.
// ---------------------------------------------------------------------------
#define VPAD 72
__device__ __forceinline__ int vswz(int row) { return ((row >> 3) & 7) * 8; }

__global__ __launch_bounds__(256) void flash_attn(
    const __hip_bfloat16* Q, const __hip_bfloat16* K, const __hip_bfloat16* V,
    const u64* mb, __hip_bfloat16* AO) {
  __shared__ __hip_bfloat16 Ks[64 * VPAD];
  __shared__ __hip_bfloat16 Vt[64 * VPAD];
  __shared__ __hip_bfloat16 Pb[4 * 16 * VPAD];

  const int tid = threadIdx.x;
  const int lane = tid & 63, w = tid >> 6;
  const int c = lane & 15, g = lane >> 4;
  const int bz = blockIdx.z, hy = blockIdx.y;
  const int q0 = blockIdx.x * 64 + w * 16;
  const long headbase = ((long)bz * NH + hy) * NS;

  const short8 qf0 = ld8(Q + (headbase + q0 + c) * ND + g * 8);
  const short8 qf1 = ld8(Q + (headbase + q0 + c) * ND + 32 + g * 8);

  floatx4 oacc[4] = {};
  float m_i[4], l_i[4];
#pragma unroll
  for (int r = 0; r < 4; ++r) { m_i[r] = -1e30f; l_i[r] = 0.f; }
  __hip_bfloat16* Pw = Pb + w * 16 * VPAD;

  for (int kt = 0; kt < 64; ++kt) {
    const int k0 = kt * 64;
#pragma unroll
    for (int it = 0; it < 2; ++it) {
      const int chunk = tid + it * 256;
      const int kc = chunk >> 3;
      const int dd = (chunk & 7) * 8;
      const long gbase = (headbase + k0 + kc) * ND + dd;
      *(uint4*)&Ks[kc * VPAD + dd] = *(const uint4*)(K + gbase);
      uint4 vv = *(const uint4*)(V + gbase);
      const __hip_bfloat16* ve = (const __hip_bfloat16*)&vv;
#pragma unroll
      for (int j = 0; j < 8; ++j) {
        const int row = dd + j;
        Vt[row * VPAD + (kc ^ vswz(row))] = ve[j];
      }
    }
    __syncthreads();

    // ---- S = Q K^T ----
    floatx4 sacc[4] = {};
#pragma unroll
    for (int t = 0; t < 4; ++t) {
      short8 b0 = ld8(&Ks[(t * 16 + c) * VPAD + g * 8]);
      sacc[t] = MFMA16(qf0, b0, sacc[t]);
      short8 b1 = ld8(&Ks[(t * 16 + c) * VPAD + 32 + g * 8]);
      sacc[t] = MFMA16(qf1, b1, sacc[t]);
    }

    // ---- mask (bit-packed) + online softmax ----
    float alpha[4];
#pragma unroll
    for (int r = 0; r < 4; ++r) {
      const int qrow = q0 + g * 4 + r;
      const u64 w64 = mb[(headbase + qrow) * 64 + kt];
      float mx = -1e30f;
#pragma unroll
      for (int t = 0; t < 4; ++t) {
        float s = sacc[t][r] * 0.125f;               // 1/sqrt(D=64)
        if ((w64 >> (t * 16 + c)) & 1ULL) s = -1e10f; // mask -> -1e10 (ref)
        sacc[t][r] = s;
        mx = fmaxf(mx, s);
      }
#pragma unroll
      for (int off = 1; off < 16; off <<= 1)
        mx = fmaxf(mx, __shfl_xor(mx, off));
      const float mn = fmaxf(m_i[r], mx);
      const float al = __expf(m_i[r] - mn);
      float ps = 0.f;
#pragma unroll
      for (int t = 0; t < 4; ++t) {
        const float p = __expf(sacc[t][r] - mn);
        sacc[t][r] = p;
        ps += p;
      }
#pragma unroll
      for (int off = 1; off < 16; off <<= 1)
        ps += __shfl_xor(ps, off);
      m_i[r] = mn;
      l_i[r] = l_i[r] * al + ps;
      alpha[r] = al;
#pragma unroll
      for (int t = 0; t < 4; ++t)
        Pw[(g * 4 + r) * VPAD + t * 16 + c] = __float2bfloat16(sacc[t][r]);
    }

#pragma unroll
    for (int t = 0; t < 4; ++t)
#pragma unroll
      for (int r = 0; r < 4; ++r) oacc[t][r] *= alpha[r];

    // Full barrier between the P LDS writes and the P LDS reads.  Pw is
    // wave-private so this is semantically a no-op across waves, but it is an
    // architecturally guaranteed write->read ordering point (compiler fence +
    // s_waitcnt + s_barrier) — removes any reliance on intra-wave DS-pipe
    // ordering assumptions.
    __syncthreads();

    // ---- O += P @ V ----
#pragma unroll
    for (int ks2 = 0; ks2 < 2; ++ks2) {
      short8 af = ld8(&Pw[c * VPAD + ks2 * 32 + g * 8]);
#pragma unroll
      for (int t = 0; t < 4; ++t) {
        const int row = t * 16 + c;
        short8 bf = ld8(&Vt[row * VPAD + ((ks2 * 32 + g * 8) ^ vswz(row))]);
        oacc[t] = MFMA16(af, bf, oacc[t]);
      }
    }
    __syncthreads();
  }

#pragma unroll
  for (int t = 0; t < 4; ++t) {
#pragma unroll
    for (int r = 0; r < 4; ++r) {
      const int qrow = q0 + g * 4 + r;
      const float v = oacc[t][r] / l_i[r];
      AO[((long)bz * NS + qrow) * NHD + hy * 64 + t * 16 + c] = __float2bfloat16(v);
    }
  }
}

// ---------------------------------------------------------------------------
// Kernel 5: output projection.  A (bf16, M x 512) @ Wo^T -> out (f32).
// ---------------------------------------------------------------------------
__global__ __launch_bounds__(256) void gemm_out(
    const __hip_bfloat16* A, const __hip_bfloat16* Wt, float* O) {
  const int lane = threadIdx.x & 63;
  const int w = threadIdx.x >> 6;
  const int c = lane & 15, g = lane >> 4;
  const int m0 = blockIdx.x * 64 + w * 16;
  const int n0 = blockIdx.y * 64;

  floatx4 acc[4] = {};
  const __hip_bfloat16* ap = A + (long)(m0 + c) * 512 + g * 8;
  const __hip_bfloat16* wp = Wt + (long)(n0 + c) * 512 + g * 8;
  for (int ks = 0; ks < 512; ks += 32) {
    short8 a = ld8(ap + ks);
#pragma unroll
    for (int t = 0; t < 4; ++t) {
      short8 b = ld8(wp + t * 16 * 512 + ks);
      acc[t] = MFMA16(a, b, acc[t]);
    }
  }
#pragma unroll
  for (int t = 0; t < 4; ++t)
#pragma unroll
    for (int r = 0; r < 4; ++r)
      O[(long)(m0 + g * 4 + r) * 512 + n0 + t * 16 + c] = acc[t][r];
}

// ---------------------------------------------------------------------------
extern "C" void kernel_launch(void* const* d_in, const int* in_sizes, int n_in,
                              void* d_out, int out_size, void* d_ws, size_t ws_size,
                              hipStream_t stream) {
  const float* q_in = (const float*)d_in[0];
  const float* k_in = (const float*)d_in[1];
  const float* v_in = (const float*)d_in[2];
  const int* mask = (const int*)d_in[3];
  const float* Wq = (const float*)d_in[4];
  const float* Wk = (const float*)d_in[5];
  const float* Wv = (const float*)d_in[6];
  const float* Wo = (const float*)d_in[7];
  float* out = (float*)d_out;

  char* base = (char*)d_ws;
  const size_t MB = 1u << 20;
  __hip_bfloat16* wtq = (__hip_bfloat16*)(base);
  __hip_bfloat16* wtk = (__hip_bfloat16*)(base + 512 * 1024);
  __hip_bfloat16* wtv = (__hip_bfloat16*)(base + 1 * MB);
  __hip_bfloat16* wto = (__hip_bfloat16*)(base + 1 * MB + 512 * 1024);
  __hip_bfloat16* qp = (__hip_bfloat16*)(base + 2 * MB);    // 8 MB each
  __hip_bfloat16* kp = (__hip_bfloat16*)(base + 10 * MB);
  __hip_bfloat16* vp = (__hip_bfloat16*)(base + 18 * MB);
  __hip_bfloat16* ao = (__hip_bfloat16*)(base + 26 * MB);
  u64* mbits = (u64*)(base + 34 * MB);                      // 32 MB

  wconv<<<dim3(8, 8, 4), 256, 0, stream>>>(Wq, Wk, Wv, Wo, wtq, wtk, wtv, wto);
  mconv<<<NB * NH * NS, 256, 0, stream>>>(mask, mbits);
  gemm_qkv<<<dim3(128, 8, 3), 256, 0, stream>>>(
      q_in, k_in, v_in, wtq, wtk, wtv, qp, kp, vp);
  flash_attn<<<dim3(NS / 64, NH, NB), 256, 0, stream>>>(qp, kp, vp, mbits, ao);
  gemm_out<<<dim3(128, 8), 256, 0, stream>>>(ao, wto, out);
}

// Round 7
// 1629.405 us; speedup vs baseline: 1.1751x; 1.1704x over previous
//
#include <hip/hip_runtime.h>
#include <hip/hip_bf16.h>

#define NB 2
#define NS 4096
#define NE 512
#define NH 8
#define ND 64
#define NHD 512

typedef __attribute__((ext_vector_type(8))) short short8;
typedef __attribute__((ext_vector_type(4))) float floatx4;

#define MFMA16(a, b, c) __builtin_amdgcn_mfma_f32_16x16x32_bf16((a), (b), (c), 0, 0, 0)

union Cvt8 { uint4 u; short8 s; };
static __device__ __forceinline__ short8 ld8(const __hip_bfloat16* p) {
  Cvt8 c; c.u = *(const uint4*)p; return c.s;
}
union BH { __hip_bfloat16 h; short s; };
static __device__ __forceinline__ short f2bs(float x) {
  BH u; u.h = __float2bfloat16(x); return u.s;
}

// ---------------------------------------------------------------------------
// Kernel 1: convert f32 -> bf16 and transpose 512x512 weights (W[k][n] -> Wt[n][k])
// ---------------------------------------------------------------------------
__global__ __launch_bounds__(256) void wconv(
    const float* w0, const float* w1, const float* w2, const float* w3,
    __hip_bfloat16* t0, __hip_bfloat16* t1,
    __hip_bfloat16* t2, __hip_bfloat16* t3) {
  __shared__ __hip_bfloat16 tile[64][72];
  const float* src;
  __hip_bfloat16* dst;
  switch (blockIdx.z) {
    case 0: src = w0; dst = t0; break;
    case 1: src = w1; dst = t1; break;
    case 2: src = w2; dst = t2; break;
    default: src = w3; dst = t3; break;
  }
  const int tx = threadIdx.x & 63, ty = threadIdx.x >> 6;
  const int n0 = blockIdx.x * 64, k0 = blockIdx.y * 64;
  for (int r = ty; r < 64; r += 4)
    tile[r][tx] = __float2bfloat16(src[(long)(k0 + r) * 512 + n0 + tx]);
  __syncthreads();
  for (int r = ty; r < 64; r += 4)
    dst[(long)(n0 + r) * 512 + k0 + tx] = tile[tx][r];
}

// ---------------------------------------------------------------------------
// Kernel 2: QKV projection GEMM.  A (f32, M x 512) @ W^T (bf16, 512 x 512)
// -> q/k/v in (B,H,S,D) bf16.  grid (M/64, 8, 3); 4 waves/block.
// ---------------------------------------------------------------------------
__global__ __launch_bounds__(256) void gemm_qkv(
    const float* A0, const float* A1, const float* A2,
    const __hip_bfloat16* W0, const __hip_bfloat16* W1, const __hip_bfloat16* W2,
    __hip_bfloat16* O0, __hip_bfloat16* O1, __hip_bfloat16* O2) {
  const float* A;
  const __hip_bfloat16* Wt;
  __hip_bfloat16* O;
  switch (blockIdx.z) {
    case 0: A = A0; Wt = W0; O = O0; break;
    case 1: A = A1; Wt = W1; O = O1; break;
    default: A = A2; Wt = W2; O = O2; break;
  }
  const int lane = threadIdx.x & 63;
  const int w = threadIdx.x >> 6;
  const int c = lane & 15, g = lane >> 4;
  const int m0 = blockIdx.x * 64 + w * 16;
  const int n0 = blockIdx.y * 64;

  floatx4 acc[4] = {};
  const float* ap = A + (long)(m0 + c) * 512 + g * 8;
  const __hip_bfloat16* wp = Wt + (long)(n0 + c) * 512 + g * 8;
  for (int ks = 0; ks < 512; ks += 32) {
    const float4 f0 = *(const float4*)(ap + ks);
    const float4 f1 = *(const float4*)(ap + ks + 4);
    short8 a;
    a[0] = f2bs(f0.x); a[1] = f2bs(f0.y); a[2] = f2bs(f0.z); a[3] = f2bs(f0.w);
    a[4] = f2bs(f1.x); a[5] = f2bs(f1.y); a[6] = f2bs(f1.z); a[7] = f2bs(f1.w);
#pragma unroll
    for (int t = 0; t < 4; ++t) {
      short8 b = ld8(wp + t * 16 * 512 + ks);
      acc[t] = MFMA16(a, b, acc[t]);
    }
  }
#pragma unroll
  for (int t = 0; t < 4; ++t) {
#pragma unroll
    for (int r = 0; r < 4; ++r) {
      const int m = m0 + g * 4 + r;
      const int n = n0 + t * 16 + c;
      const int bb = m >> 12, s = m & 4095, h = n >> 6, d = n & 63;
      O[(((long)bb * NH + h) * NS + s) * ND + d] = __float2bfloat16(acc[t][r]);
    }
  }
}

// ---------------------------------------------------------------------------
// Kernel 3: fused flash attention; int32 mask read directly (streamed).
// grid (S/64, H, B); block 256 = 4 waves; wave handles 16 q-rows.
// P round-trip protected by a real __syncthreads (not a compiler fence).
// ---------------------------------------------------------------------------
#define VPAD 72
__device__ __forceinline__ int vswz(int row) { return ((row >> 3) & 7) * 8; }

__global__ __launch_bounds__(256) void flash_attn(
    const __hip_bfloat16* Q, const __hip_bfloat16* K, const __hip_bfloat16* V,
    const int* mask, __hip_bfloat16* AO) {
  __shared__ __hip_bfloat16 Ks[64 * VPAD];
  __shared__ __hip_bfloat16 Vt[64 * VPAD];
  __shared__ __hip_bfloat16 Pb[4 * 16 * VPAD];

  const int tid = threadIdx.x;
  const int lane = tid & 63, w = tid >> 6;
  const int c = lane & 15, g = lane >> 4;
  const int bz = blockIdx.z, hy = blockIdx.y;
  const int q0 = blockIdx.x * 64 + w * 16;
  const long headbase = ((long)bz * NH + hy) * NS;

  const short8 qf0 = ld8(Q + (headbase + q0 + c) * ND + g * 8);
  const short8 qf1 = ld8(Q + (headbase + q0 + c) * ND + 32 + g * 8);

  floatx4 oacc[4] = {};
  float m_i[4], l_i[4];
#pragma unroll
  for (int r = 0; r < 4; ++r) { m_i[r] = -1e30f; l_i[r] = 0.f; }
  __hip_bfloat16* Pw = Pb + w * 16 * VPAD;

  for (int kt = 0; kt < 64; ++kt) {
    const int k0 = kt * 64;
#pragma unroll
    for (int it = 0; it < 2; ++it) {
      const int chunk = tid + it * 256;
      const int kc = chunk >> 3;
      const int dd = (chunk & 7) * 8;
      const long gbase = (headbase + k0 + kc) * ND + dd;
      *(uint4*)&Ks[kc * VPAD + dd] = *(const uint4*)(K + gbase);
      uint4 vv = *(const uint4*)(V + gbase);
      const __hip_bfloat16* ve = (const __hip_bfloat16*)&vv;
#pragma unroll
      for (int j = 0; j < 8; ++j) {
        const int row = dd + j;
        Vt[row * VPAD + (kc ^ vswz(row))] = ve[j];
      }
    }
    __syncthreads();

    // ---- S = Q K^T ----
    floatx4 sacc[4] = {};
#pragma unroll
    for (int t = 0; t < 4; ++t) {
      short8 b0 = ld8(&Ks[(t * 16 + c) * VPAD + g * 8]);
      sacc[t] = MFMA16(qf0, b0, sacc[t]);
      short8 b1 = ld8(&Ks[(t * 16 + c) * VPAD + 32 + g * 8]);
      sacc[t] = MFMA16(qf1, b1, sacc[t]);
    }

    // ---- mask (direct int32 read) + online softmax ----
    float alpha[4];
#pragma unroll
    for (int r = 0; r < 4; ++r) {
      const int qrow = q0 + g * 4 + r;
      const int* mrow = mask + (headbase + qrow) * NS + k0 + c;
      float mx = -1e30f;
#pragma unroll
      for (int t = 0; t < 4; ++t) {
        float s = sacc[t][r] * 0.125f;       // 1/sqrt(D=64)
        if (mrow[t * 16] != 0) s = -1e10f;   // mask==true -> -1e10 (ref)
        sacc[t][r] = s;
        mx = fmaxf(mx, s);
      }
#pragma unroll
      for (int off = 1; off < 16; off <<= 1)
        mx = fmaxf(mx, __shfl_xor(mx, off));
      const float mn = fmaxf(m_i[r], mx);
      const float al = __expf(m_i[r] - mn);
      float ps = 0.f;
#pragma unroll
      for (int t = 0; t < 4; ++t) {
        const float p = __expf(sacc[t][r] - mn);
        sacc[t][r] = p;
        ps += p;
      }
#pragma unroll
      for (int off = 1; off < 16; off <<= 1)
        ps += __shfl_xor(ps, off);
      m_i[r] = mn;
      l_i[r] = l_i[r] * al + ps;
      alpha[r] = al;
#pragma unroll
      for (int t = 0; t < 4; ++t)
        Pw[(g * 4 + r) * VPAD + t * 16 + c] = __float2bfloat16(sacc[t][r]);
    }

#pragma unroll
    for (int t = 0; t < 4; ++t)
#pragma unroll
      for (int r = 0; r < 4; ++r) oacc[t][r] *= alpha[r];

    // Real barrier between P LDS writes and P LDS reads (architecturally
    // guaranteed ordering point; the asm-only fence is build-fragile).
    __syncthreads();

    // ---- O += P @ V ----
#pragma unroll
    for (int ks2 = 0; ks2 < 2; ++ks2) {
      short8 af = ld8(&Pw[c * VPAD + ks2 * 32 + g * 8]);
#pragma unroll
      for (int t = 0; t < 4; ++t) {
        const int row = t * 16 + c;
        short8 bf = ld8(&Vt[row * VPAD + ((ks2 * 32 + g * 8) ^ vswz(row))]);
        oacc[t] = MFMA16(af, bf, oacc[t]);
      }
    }
    __syncthreads();
  }

#pragma unroll
  for (int t = 0; t < 4; ++t) {
#pragma unroll
    for (int r = 0; r < 4; ++r) {
      const int qrow = q0 + g * 4 + r;
      const float v = oacc[t][r] / l_i[r];
      AO[((long)bz * NS + qrow) * NHD + hy * 64 + t * 16 + c] = __float2bfloat16(v);
    }
  }
}

// ---------------------------------------------------------------------------
// Kernel 4: output projection.  A (bf16, M x 512) @ Wo^T -> out (f32).
// ---------------------------------------------------------------------------
__global__ __launch_bounds__(256) void gemm_out(
    const __hip_bfloat16* A, const __hip_bfloat16* Wt, float* O) {
  const int lane = threadIdx.x & 63;
  const int w = threadIdx.x >> 6;
  const int c = lane & 15, g = lane >> 4;
  const int m0 = blockIdx.x * 64 + w * 16;
  const int n0 = blockIdx.y * 64;

  floatx4 acc[4] = {};
  const __hip_bfloat16* ap = A + (long)(m0 + c) * 512 + g * 8;
  const __hip_bfloat16* wp = Wt + (long)(n0 + c) * 512 + g * 8;
  for (int ks = 0; ks < 512; ks += 32) {
    short8 a = ld8(ap + ks);
#pragma unroll
    for (int t = 0; t < 4; ++t) {
      short8 b = ld8(wp + t * 16 * 512 + ks);
      acc[t] = MFMA16(a, b, acc[t]);
    }
  }
#pragma unroll
  for (int t = 0; t < 4; ++t)
#pragma unroll
    for (int r = 0; r < 4; ++r)
      O[(long)(m0 + g * 4 + r) * 512 + n0 + t * 16 + c] = acc[t][r];
}

// ---------------------------------------------------------------------------
extern "C" void kernel_launch(void* const* d_in, const int* in_sizes, int n_in,
                              void* d_out, int out_size, void* d_ws, size_t ws_size,
                              hipStream_t stream) {
  const float* q_in = (const float*)d_in[0];
  const float* k_in = (const float*)d_in[1];
  const float* v_in = (const float*)d_in[2];
  const int* mask = (const int*)d_in[3];
  const float* Wq = (const float*)d_in[4];
  const float* Wk = (const float*)d_in[5];
  const float* Wv = (const float*)d_in[6];
  const float* Wo = (const float*)d_in[7];
  float* out = (float*)d_out;

  char* base = (char*)d_ws;
  const size_t MB = 1u << 20;
  __hip_bfloat16* wtq = (__hip_bfloat16*)(base);
  __hip_bfloat16* wtk = (__hip_bfloat16*)(base + 512 * 1024);
  __hip_bfloat16* wtv = (__hip_bfloat16*)(base + 1 * MB);
  __hip_bfloat16* wto = (__hip_bfloat16*)(base + 1 * MB + 512 * 1024);
  __hip_bfloat16* qp = (__hip_bfloat16*)(base + 2 * MB);    // 8 MB each
  __hip_bfloat16* kp = (__hip_bfloat16*)(base + 10 * MB);
  __hip_bfloat16* vp = (__hip_bfloat16*)(base + 18 * MB);
  __hip_bfloat16* ao = (__hip_bfloat16*)(base + 26 * MB);

  wconv<<<dim3(8, 8, 4), 256, 0, stream>>>(Wq, Wk, Wv, Wo, wtq, wtk, wtv, wto);
  gemm_qkv<<<dim3(128, 8, 3), 256, 0, stream>>>(
      q_in, k_in, v_in, wtq, wtk, wtv, qp, kp, vp);
  flash_attn<<<dim3(NS / 64, NH, NB), 256, 0, stream>>>(qp, kp, vp, mask, ao);
  gemm_out<<<dim3(128, 8), 256, 0, stream>>>(ao, wto, out);
}